// Round 1
// baseline (4801.247 us; speedup 1.0000x reference)
//
#include <hip/hip_runtime.h>
#include <math.h>

#define N_ 5
#define A_ 900
#define AD_ 8
#define D_ 256
#define H_ 8
#define DH_ 32
#define K_ 300
#define NM1_ 4
#define M_ 1200  // K_*(N_-1)

// ---------------- scores: sigmoid(b_feature @ w_roi + b_roi) ----------------
__global__ __launch_bounds__(256) void score_kernel(const float* __restrict__ bf,
                                                    const float* __restrict__ w,
                                                    const float* __restrict__ b,
                                                    float* __restrict__ scores) {
  int wid = threadIdx.x >> 6, lane = threadIdx.x & 63;
  int row = blockIdx.x * 4 + wid;
  if (row >= N_ * A_) return;
  const float* x = bf + (long)row * D_;
  float dot = 0.f;
#pragma unroll
  for (int t = 0; t < 4; t++) dot += x[lane + 64 * t] * w[lane + 64 * t];
#pragma unroll
  for (int o = 32; o; o >>= 1) dot += __shfl_xor(dot, o, 64);
  if (lane == 0) scores[row] = 1.0f / (1.0f + expf(-(dot + b[0])));
}

// ---------------- top-k via bitonic sort (1 block per batch row) ----------------
__global__ __launch_bounds__(1024) void topk_kernel(const float* __restrict__ scores,
                                                    int* __restrict__ top_idx,
                                                    float* __restrict__ conf) {
  __shared__ float sc[1024];
  __shared__ int si[1024];
  int i = blockIdx.x, t = threadIdx.x;
  sc[t] = (t < A_) ? scores[i * A_ + t] : -INFINITY;
  si[t] = t;
  __syncthreads();
  for (int k = 2; k <= 1024; k <<= 1) {
    for (int j = k >> 1; j > 0; j >>= 1) {
      int ixj = t ^ j;
      if (ixj > t) {
        bool dir = ((t & k) == 0);  // true -> descending segment
        float a = sc[t], b = sc[ixj];
        bool sw = dir ? (a < b) : (a > b);
        if (sw) {
          sc[t] = b; sc[ixj] = a;
          int tmp = si[t]; si[t] = si[ixj]; si[ixj] = tmp;
        }
      }
      __syncthreads();
    }
  }
  if (t < K_) {
    top_idx[i * K_ + t] = si[t];
    conf[i * K_ + t] = sc[t] > 0.5f ? 1.0f : 0.0f;
  }
}

// ---------------- tiny MLP on transform matrices ----------------
__global__ __launch_bounds__(256) void mlp_kernel(const float* __restrict__ tm,
                                                  const float* __restrict__ bn_g, const float* __restrict__ bn_b,
                                                  const float* __restrict__ fc1_w, const float* __restrict__ fc1_b,
                                                  const float* __restrict__ fc2_w, const float* __restrict__ fc2_b,
                                                  float* __restrict__ t_out) {
  __shared__ float x[20][12], y[20][12];
  __shared__ float hbuf[20][D_];
  __shared__ float mu[12], rstd[12];
  int t = threadIdx.x;
  if (t < 240) {
    int r = t / 12, f = t % 12;
    int i = r / NM1_, jj = r % NM1_;
    int j = jj < i ? jj : jj + 1;
    int rr = f / 4, cc = f % 4;
    x[r][f] = tm[((long)(i * N_ + j) * 4 + rr) * 4 + cc];
  }
  __syncthreads();
  if (t < 12) {
    float s = 0.f;
    for (int r = 0; r < 20; r++) s += x[r][t];
    float m = s / 20.0f;
    float v = 0.f;
    for (int r = 0; r < 20; r++) { float d = x[r][t] - m; v += d * d; }
    v /= 20.0f;
    mu[t] = m;
    rstd[t] = rsqrtf(v + 1e-5f);
  }
  __syncthreads();
  if (t < 240) {
    int r = t / 12, f = t % 12;
    y[r][f] = (x[r][f] - mu[f]) * rstd[f] * bn_g[f] + bn_b[f];
  }
  __syncthreads();
  for (int r = 0; r < 20; r++) {
    float acc = fc1_b[t];
#pragma unroll
    for (int f = 0; f < 12; f++) acc += y[r][f] * fc1_w[f * D_ + t];
    hbuf[r][t] = fmaxf(acc, 0.0f);
  }
  __syncthreads();
  for (int r = 0; r < 20; r++) {
    float acc = fc2_b[t];
    for (int k = 0; k < D_; k++) acc += hbuf[r][k] * fc2_w[k * D_ + t];
    t_out[r * D_ + t] = acc;
  }
}

// ---------------- bbox min/max ----------------
__global__ void bbox_kernel(const float* __restrict__ ban, float* __restrict__ mn, float* __restrict__ mx) {
  int idx = blockIdx.x * blockDim.x + threadIdx.x;
  if (idx >= N_ * A_) return;
  const float* a = ban + (long)idx * AD_;
  float x = a[0], y = a[1], z = a[2];
  float w = expf(a[3]), l = expf(a[4]), h = expf(a[5]);
  float yaw = atan2f(a[6], a[7]);
  float ca = fabsf(cosf(yaw)), sa = fabsf(sinf(yaw));
  float ex = 0.5f * (l * ca + w * sa);
  float ey = 0.5f * (l * sa + w * ca);
  float ez = 0.5f * h;
  mn[idx * 3 + 0] = x - ex; mn[idx * 3 + 1] = y - ey; mn[idx * 3 + 2] = z - ez;
  mx[idx * 3 + 0] = x + ex; mx[idx * 3 + 1] = y + ey; mx[idx * 3 + 2] = z + ez;
}

// ---------------- gather: key_feat, nf_masked, i2j_rm, key_in ----------------
__global__ __launch_bounds__(256) void gather_kernel(const float* __restrict__ b_feature,
                                                     const float* __restrict__ i2j_anchor,
                                                     const int* __restrict__ top_idx,
                                                     const float* __restrict__ conf,
                                                     const float* __restrict__ anc_w,
                                                     const float* __restrict__ anc_b,
                                                     const float* __restrict__ t_mlp,
                                                     float* __restrict__ key_feat,
                                                     float* __restrict__ nf_masked,
                                                     float* __restrict__ i2j_rm,
                                                     float* __restrict__ key_in) {
  int blk = blockIdx.x;  // i*4+jj
  int i = blk / NM1_, jj = blk % NM1_;
  int j = jj < i ? jj : jj + 1;
  int c = threadIdx.x;
  __shared__ float aw[AD_][D_];
#pragma unroll
  for (int r = 0; r < AD_; r++) aw[r][c] = anc_w[r * D_ + c];
  float ab = anc_b[c];
  float tv = t_mlp[(i * NM1_ + jj) * D_ + c];
  __syncthreads();
  for (int k = 0; k < K_; k++) {
    int idx = top_idx[j * K_ + k];
    float cf = conf[j * K_ + k];
    const float* src = b_feature + ((long)(j * A_ + idx)) * D_;
    float val = src[c];
    long mrow = (long)i * M_ + jj * K_ + k;
    key_feat[mrow * D_ + c] = val;
    nf_masked[mrow * D_ + c] = val * cf;
    const float* ap = i2j_anchor + ((long)((i * N_ + j) * A_ + idx)) * AD_;
    if (c < AD_) i2j_rm[mrow * AD_ + c] = ap[c];
    float pos = ab + tv;
#pragma unroll
    for (int r = 0; r < AD_; r++) pos += ap[r] * aw[r][c];
    key_in[mrow * D_ + c] = val + pos;
  }
}

// ---------------- inside mask (f32 0/1) ----------------
__global__ __launch_bounds__(256) void inside_kernel(const float* __restrict__ i2j_rm,
                                                     const float* __restrict__ mn,
                                                     const float* __restrict__ mx,
                                                     float* __restrict__ inside) {
  int row = blockIdx.x;  // i*900+a
  int i = row / A_;
  float mn0 = mn[row * 3 + 0], mn1 = mn[row * 3 + 1], mn2 = mn[row * 3 + 2];
  float mx0 = mx[row * 3 + 0], mx1 = mx[row * 3 + 1], mx2 = mx[row * 3 + 2];
#pragma unroll
  for (int it = 0; it < 5; it++) {
    int m = it * 256 + threadIdx.x;
    if (m < M_) {
      const float* cp = i2j_rm + ((long)i * M_ + m) * AD_;
      float c0 = cp[0], c1 = cp[1], c2 = cp[2];
      bool ins = (c0 >= mn0) && (c0 <= mx0) && (c1 >= mn1) && (c1 <= mx1) && (c2 >= mn2) && (c2 <= mx2);
      inside[(long)row * M_ + m] = ins ? 1.0f : 0.0f;
    }
  }
}

// ---------------- generic batched GEMM: C = A@B (+bias) (+res) ----------------
__global__ __launch_bounds__(256) void gemm_kernel(const float* __restrict__ A,
                                                   const float* __restrict__ B,
                                                   const float* __restrict__ bias,
                                                   const float* __restrict__ res,
                                                   float* __restrict__ C,
                                                   int Mr, int Nc, int Kc,
                                                   long sA, long sB, long sC) {
  int bz = blockIdx.z;
  A += (long)bz * sA;
  B += (long)bz * sB;
  C += (long)bz * sC;
  if (res) res += (long)bz * sC;
  __shared__ float As[16][65];
  __shared__ float Bs[16][65];
  int m0 = blockIdx.x * 64, n0 = blockIdx.y * 64;
  int tid = threadIdx.x;
  int tx = tid % 16, ty = tid / 16;
  float acc[4][4] = {};
  for (int k0 = 0; k0 < Kc; k0 += 16) {
#pragma unroll
    for (int r = 0; r < 4; r++) {
      int l = r * 256 + tid;
      int mm = l >> 4, kk = l & 15;
      int gm = m0 + mm, gk = k0 + kk;
      As[kk][mm] = (gm < Mr && gk < Kc) ? A[(long)gm * Kc + gk] : 0.0f;
    }
#pragma unroll
    for (int r = 0; r < 4; r++) {
      int l = r * 256 + tid;
      int nn = l & 63, kk = l >> 6;
      int gk = k0 + kk, gn = n0 + nn;
      Bs[kk][nn] = (gk < Kc && gn < Nc) ? B[(long)gk * Nc + gn] : 0.0f;
    }
    __syncthreads();
#pragma unroll
    for (int kk = 0; kk < 16; kk++) {
      float av[4], bv[4];
#pragma unroll
      for (int ii = 0; ii < 4; ii++) av[ii] = As[kk][ty * 4 + ii];
#pragma unroll
      for (int jjv = 0; jjv < 4; jjv++) bv[jjv] = Bs[kk][tx * 4 + jjv];
#pragma unroll
      for (int ii = 0; ii < 4; ii++)
#pragma unroll
        for (int jjv = 0; jjv < 4; jjv++) acc[ii][jjv] += av[ii] * bv[jjv];
    }
    __syncthreads();
  }
#pragma unroll
  for (int ii = 0; ii < 4; ii++) {
    int gm = m0 + ty * 4 + ii;
    if (gm >= Mr) continue;
#pragma unroll
    for (int jjv = 0; jjv < 4; jjv++) {
      int gn = n0 + tx * 4 + jjv;
      if (gn >= Nc) continue;
      float v = acc[ii][jjv];
      if (bias) v += bias[gn];
      if (res) v += res[(long)gm * Nc + gn];
      C[(long)gm * Nc + gn] = v;
    }
  }
}

// ---------------- elementwise add ----------------
__global__ void add_kernel(const float* __restrict__ a, const float* __restrict__ b,
                           float* __restrict__ c, int n) {
  int i = blockIdx.x * 256 + threadIdx.x;
  if (i < n) c[i] = a[i] + b[i];
}

// ---------------- head transpose: (N,M,256) -> (N,H,32,M) ----------------
__global__ __launch_bounds__(256) void trans_kernel(const float* __restrict__ src, float* __restrict__ dst) {
  int ih = blockIdx.x;  // i*8+h
  int i = ih / H_, h = ih % H_;
  int m0 = blockIdx.y * 64;
  __shared__ float lds[64][33];
  int tid = threadIdx.x;
#pragma unroll
  for (int r = 0; r < 8; r++) {
    int l = r * 256 + tid;
    int ml = l >> 5, dl = l & 31;
    int m = m0 + ml;
    if (m < M_) lds[ml][dl] = src[((long)i * M_ + m) * D_ + h * DH_ + dl];
  }
  __syncthreads();
#pragma unroll
  for (int r = 0; r < 8; r++) {
    int l = r * 256 + tid;
    int ml2 = l & 63, dl2 = l >> 6;
    int m = m0 + ml2;
    if (m < M_) dst[((long)ih * DH_ + dl2) * M_ + m] = lds[ml2][dl2];
  }
}

// ---------------- attention: one wave per (i,h,a) ----------------
__global__ __launch_bounds__(256) void attn_kernel(const float* __restrict__ qh,
                                                   const float* __restrict__ khT,
                                                   const float* __restrict__ vhT,
                                                   const float* __restrict__ lm_rm,
                                                   const float* __restrict__ ban,
                                                   const float* __restrict__ i2j_rm,
                                                   float* __restrict__ out) {
  int wid = threadIdx.x >> 6, lane = threadIdx.x & 63;
  int blk = blockIdx.x;
  int ag = blk % 225;
  int ih = blk / 225;
  int i = ih >> 3, h = ih & 7;
  int a = ag * 4 + wid;
  const float* qp = qh + ((long)(i * A_ + a)) * D_ + h * DH_;
  float q[DH_];
#pragma unroll
  for (int d = 0; d < DH_; d++) q[d] = qp[d];
  float lmv = lm_rm[(long)(i * A_ + a) * H_ + h];
  float ax = ban[(long)(i * A_ + a) * AD_ + 0];
  float ay = ban[(long)(i * A_ + a) * AD_ + 1];
  const float* kbase = khT + (long)ih * DH_ * M_;
  const float* vbase = vhT + (long)ih * DH_ * M_;
  float lg[19];
#pragma unroll
  for (int ch = 0; ch < 19; ch++) {
    int m = ch * 64 + lane;
    if (m < M_) {
      float dot = 0.f;
#pragma unroll
      for (int d = 0; d < DH_; d++) dot += q[d] * kbase[(long)d * M_ + m];
      const float* cp = i2j_rm + ((long)i * M_ + m) * AD_;
      float dx = ax - cp[0], dy = ay - cp[1];
      float dist = sqrtf(dx * dx + dy * dy + 1e-12f);
      lg[ch] = dot * 0.17677669529663687f - log1pf(dist) * lmv;
    } else {
      lg[ch] = -INFINITY;
    }
  }
  float mxv = lg[0];
#pragma unroll
  for (int ch = 1; ch < 19; ch++) mxv = fmaxf(mxv, lg[ch]);
#pragma unroll
  for (int o = 32; o; o >>= 1) mxv = fmaxf(mxv, __shfl_xor(mxv, o, 64));
  float p[19];
  float s = 0.f;
#pragma unroll
  for (int ch = 0; ch < 19; ch++) {
    int m = ch * 64 + lane;
    p[ch] = (m < M_) ? expf(lg[ch] - mxv) : 0.0f;
    s += p[ch];
  }
#pragma unroll
  for (int o = 32; o; o >>= 1) s += __shfl_xor(s, o, 64);
  float inv = 1.0f / s;
  float myout = 0.f;
#pragma unroll
  for (int d = 0; d < DH_; d++) {
    float part = 0.f;
#pragma unroll
    for (int ch = 0; ch < 19; ch++) {
      int m = ch * 64 + lane;
      if (m < M_) part += p[ch] * vbase[(long)d * M_ + m];
    }
#pragma unroll
    for (int o = 32; o; o >>= 1) part += __shfl_xor(part, o, 64);
    if (lane == d) myout = part * inv;
  }
  if (lane < DH_) out[((long)(i * A_ + a)) * D_ + h * DH_ + lane] = myout;
}

// ---------------- LayerNorm ----------------
__global__ __launch_bounds__(256) void ln_kernel(const float* __restrict__ x,
                                                 const float* __restrict__ g,
                                                 const float* __restrict__ b,
                                                 float* __restrict__ out) {
  int row = blockIdx.x;
  int t = threadIdx.x;
  float v = x[(long)row * D_ + t];
  float s = v, sq = v * v;
#pragma unroll
  for (int o = 32; o; o >>= 1) {
    s += __shfl_xor(s, o, 64);
    sq += __shfl_xor(sq, o, 64);
  }
  __shared__ float ss[4], ssq[4];
  int wid = t >> 6, lane = t & 63;
  if (lane == 0) { ss[wid] = s; ssq[wid] = sq; }
  __syncthreads();
  float ts = ss[0] + ss[1] + ss[2] + ss[3];
  float tq = ssq[0] + ssq[1] + ssq[2] + ssq[3];
  float mean = ts / (float)D_;
  float var = tq / (float)D_ - mean * mean;
  out[(long)row * D_ + t] = (v - mean) * rsqrtf(var + 1e-5f) * g[t] + b[t];
}

extern "C" void kernel_launch(void* const* d_in, const int* in_sizes, int n_in,
                              void* d_out, int out_size, void* d_ws, size_t ws_size,
                              hipStream_t stream) {
  const float* i2j_anchor   = (const float*)d_in[0];
  const float* b_anchor     = (const float*)d_in[1];
  const float* b_feature    = (const float*)d_in[2];
  const float* tm           = (const float*)d_in[3];
  const float* anchor_embed = (const float*)d_in[4];
  const float* w_roi  = (const float*)d_in[5];
  const float* b_roi  = (const float*)d_in[6];
  const float* bn_g   = (const float*)d_in[7];
  const float* bn_b   = (const float*)d_in[8];
  const float* fc1_w  = (const float*)d_in[9];
  const float* fc1_b  = (const float*)d_in[10];
  const float* fc2_w  = (const float*)d_in[11];
  const float* fc2_b  = (const float*)d_in[12];
  const float* anc_w  = (const float*)d_in[13];
  const float* anc_b  = (const float*)d_in[14];
  const float* lam_w  = (const float*)d_in[15];
  const float* lam_b  = (const float*)d_in[16];
  const float* wq = (const float*)d_in[17];
  const float* bq = (const float*)d_in[18];
  const float* wk = (const float*)d_in[19];
  const float* bk = (const float*)d_in[20];
  const float* wv = (const float*)d_in[21];
  const float* bv = (const float*)d_in[22];
  const float* wo = (const float*)d_in[23];
  const float* bo = (const float*)d_in[24];
  const float* ln_g = (const float*)d_in[25];
  const float* ln_b = (const float*)d_in[26];

  float* ws = (float*)d_ws;
  size_t off = 0;
  auto alloc = [&](size_t n) { float* p = ws + off; off += n; return p; };

  float* scores    = alloc(N_ * A_);
  int*   top_idx   = (int*)alloc(N_ * K_);
  float* conf      = alloc(N_ * K_);
  float* t_mlp     = alloc(20 * D_);
  float* bmn       = alloc(N_ * A_ * 3);
  float* bmx       = alloc(N_ * A_ * 3);
  float* key_feat  = alloc((size_t)N_ * M_ * D_);
  float* nf_masked = alloc((size_t)N_ * M_ * D_);
  float* i2j_rm    = alloc((size_t)N_ * M_ * AD_);
  float* key_in    = alloc((size_t)N_ * M_ * D_);
  float* inside    = alloc((size_t)N_ * A_ * M_);
  float* bf_upd    = alloc((size_t)N_ * A_ * D_);
  float* q_in      = alloc((size_t)N_ * A_ * D_);
  float* qhb       = alloc((size_t)N_ * A_ * D_);
  float* kh_rm     = alloc((size_t)N_ * M_ * D_);
  float* vh_rm     = alloc((size_t)N_ * M_ * D_);
  float* khT       = alloc((size_t)N_ * M_ * D_);
  float* vhT       = alloc((size_t)N_ * M_ * D_);
  float* lm_rm     = alloc((size_t)N_ * A_ * H_);
  float* att_out   = alloc((size_t)N_ * A_ * D_);
  float* res_buf   = alloc((size_t)N_ * A_ * D_);

  // 1. scores
  score_kernel<<<(N_ * A_ + 3) / 4, 256, 0, stream>>>(b_feature, w_roi, b_roi, scores);
  // 2. top-k
  topk_kernel<<<N_, 1024, 0, stream>>>(scores, top_idx, conf);
  // 3. tiny MLP
  mlp_kernel<<<1, 256, 0, stream>>>(tm, bn_g, bn_b, fc1_w, fc1_b, fc2_w, fc2_b, t_mlp);
  // 4. bbox
  bbox_kernel<<<(N_ * A_ + 255) / 256, 256, 0, stream>>>(b_anchor, bmn, bmx);
  // 5. gather
  gather_kernel<<<N_ * NM1_, 256, 0, stream>>>(b_feature, i2j_anchor, top_idx, conf,
                                               anc_w, anc_b, t_mlp,
                                               key_feat, nf_masked, i2j_rm, key_in);
  // 6. inside mask
  inside_kernel<<<N_ * A_, 256, 0, stream>>>(i2j_rm, bmn, bmx, inside);
  // 7. agg GEMM: bf_upd = inside @ nf_masked + b_feature   (batched over i)
  gemm_kernel<<<dim3(15, 4, N_), 256, 0, stream>>>(inside, nf_masked, nullptr, b_feature, bf_upd,
                                                   A_, D_, M_,
                                                   (long)A_ * M_, (long)M_ * D_, (long)A_ * D_);
  // 8. q_in = bf_upd + anchor_embed
  add_kernel<<<(N_ * A_ * D_ + 255) / 256, 256, 0, stream>>>(bf_upd, anchor_embed, q_in, N_ * A_ * D_);
  // 9. lm = bf_upd @ lam_w + lam_b   (4500 x 8)
  gemm_kernel<<<dim3(71, 1, 1), 256, 0, stream>>>(bf_upd, lam_w, lam_b, nullptr, lm_rm,
                                                  N_ * A_, H_, D_, 0, 0, 0);
  // 10. qh = q_in @ wq + bq
  gemm_kernel<<<dim3(71, 4, 1), 256, 0, stream>>>(q_in, wq, bq, nullptr, qhb,
                                                  N_ * A_, D_, D_, 0, 0, 0);
  // 11. kh = key_in @ wk + bk
  gemm_kernel<<<dim3(94, 4, 1), 256, 0, stream>>>(key_in, wk, bk, nullptr, kh_rm,
                                                  N_ * M_, D_, D_, 0, 0, 0);
  // 12. vh = key_feat @ wv + bv
  gemm_kernel<<<dim3(94, 4, 1), 256, 0, stream>>>(key_feat, wv, bv, nullptr, vh_rm,
                                                  N_ * M_, D_, D_, 0, 0, 0);
  // 13. transpose to (i,h,d,m)
  trans_kernel<<<dim3(N_ * H_, 19), 256, 0, stream>>>(kh_rm, khT);
  trans_kernel<<<dim3(N_ * H_, 19), 256, 0, stream>>>(vh_rm, vhT);
  // 14. attention
  attn_kernel<<<N_ * H_ * (A_ / 4), 256, 0, stream>>>(qhb, khT, vhT, lm_rm, b_anchor, i2j_rm, att_out);
  // 15. out projection + residual
  gemm_kernel<<<dim3(71, 4, 1), 256, 0, stream>>>(att_out, wo, bo, bf_upd, res_buf,
                                                  N_ * A_, D_, D_, 0, 0, 0);
  // 16. LayerNorm -> d_out
  ln_kernel<<<N_ * A_, 256, 0, stream>>>(res_buf, ln_g, ln_b, (float*)d_out);
}

// Round 2
// 1068.490 us; speedup vs baseline: 4.4935x; 4.4935x over previous
//
#include <hip/hip_runtime.h>
#include <math.h>

#define N_ 5
#define A_ 900
#define AD_ 8
#define D_ 256
#define H_ 8
#define DH_ 32
#define K_ 300
#define NM1_ 4
#define M_ 1200  // K_*(N_-1)

#define MC_ 25      // m-chunk per LDS stage
#define QT_ 64      // queries per block
#define HALFM_ 600  // M_/2
#define CHUNKS_ 24  // HALFM_/MC_

// ---------------- scores: sigmoid(b_feature @ w_roi + b_roi) ----------------
__global__ __launch_bounds__(256) void score_kernel(const float* __restrict__ bf,
                                                    const float* __restrict__ w,
                                                    const float* __restrict__ b,
                                                    float* __restrict__ scores) {
  int wid = threadIdx.x >> 6, lane = threadIdx.x & 63;
  int row = blockIdx.x * 4 + wid;
  if (row >= N_ * A_) return;
  const float* x = bf + (long)row * D_;
  float dot = 0.f;
#pragma unroll
  for (int t = 0; t < 4; t++) dot += x[lane + 64 * t] * w[lane + 64 * t];
#pragma unroll
  for (int o = 32; o; o >>= 1) dot += __shfl_xor(dot, o, 64);
  if (lane == 0) scores[row] = 1.0f / (1.0f + expf(-(dot + b[0])));
}

// ---------------- top-k via bitonic sort (1 block per batch row) ----------------
__global__ __launch_bounds__(1024) void topk_kernel(const float* __restrict__ scores,
                                                    int* __restrict__ top_idx,
                                                    float* __restrict__ conf) {
  __shared__ float sc[1024];
  __shared__ int si[1024];
  int i = blockIdx.x, t = threadIdx.x;
  sc[t] = (t < A_) ? scores[i * A_ + t] : -INFINITY;
  si[t] = t;
  __syncthreads();
  for (int k = 2; k <= 1024; k <<= 1) {
    for (int j = k >> 1; j > 0; j >>= 1) {
      int ixj = t ^ j;
      if (ixj > t) {
        bool dir = ((t & k) == 0);
        float a = sc[t], b = sc[ixj];
        bool sw = dir ? (a < b) : (a > b);
        if (sw) {
          sc[t] = b; sc[ixj] = a;
          int tmp = si[t]; si[t] = si[ixj]; si[ixj] = tmp;
        }
      }
      __syncthreads();
    }
  }
  if (t < K_) {
    top_idx[i * K_ + t] = si[t];
    conf[i * K_ + t] = sc[t] > 0.5f ? 1.0f : 0.0f;
  }
}

// ---------------- tiny MLP on transform matrices ----------------
__global__ __launch_bounds__(256) void mlp_kernel(const float* __restrict__ tm,
                                                  const float* __restrict__ bn_g, const float* __restrict__ bn_b,
                                                  const float* __restrict__ fc1_w, const float* __restrict__ fc1_b,
                                                  const float* __restrict__ fc2_w, const float* __restrict__ fc2_b,
                                                  float* __restrict__ t_out) {
  __shared__ float x[20][12], y[20][12];
  __shared__ float hbuf[20][D_];
  __shared__ float mu[12], rstd[12];
  int t = threadIdx.x;
  if (t < 240) {
    int r = t / 12, f = t % 12;
    int i = r / NM1_, jj = r % NM1_;
    int j = jj < i ? jj : jj + 1;
    int rr = f / 4, cc = f % 4;
    x[r][f] = tm[((long)(i * N_ + j) * 4 + rr) * 4 + cc];
  }
  __syncthreads();
  if (t < 12) {
    float s = 0.f;
    for (int r = 0; r < 20; r++) s += x[r][t];
    float m = s / 20.0f;
    float v = 0.f;
    for (int r = 0; r < 20; r++) { float d = x[r][t] - m; v += d * d; }
    v /= 20.0f;
    mu[t] = m;
    rstd[t] = rsqrtf(v + 1e-5f);
  }
  __syncthreads();
  if (t < 240) {
    int r = t / 12, f = t % 12;
    y[r][f] = (x[r][f] - mu[f]) * rstd[f] * bn_g[f] + bn_b[f];
  }
  __syncthreads();
  for (int r = 0; r < 20; r++) {
    float acc = fc1_b[t];
#pragma unroll
    for (int f = 0; f < 12; f++) acc += y[r][f] * fc1_w[f * D_ + t];
    hbuf[r][t] = fmaxf(acc, 0.0f);
  }
  __syncthreads();
  for (int r = 0; r < 20; r++) {
    float acc = fc2_b[t];
    for (int k = 0; k < D_; k++) acc += hbuf[r][k] * fc2_w[k * D_ + t];
    t_out[r * D_ + t] = acc;
  }
}

// ---------------- bbox min/max ----------------
__global__ void bbox_kernel(const float* __restrict__ ban, float* __restrict__ mn, float* __restrict__ mx) {
  int idx = blockIdx.x * blockDim.x + threadIdx.x;
  if (idx >= N_ * A_) return;
  const float* a = ban + (long)idx * AD_;
  float x = a[0], y = a[1], z = a[2];
  float w = expf(a[3]), l = expf(a[4]), h = expf(a[5]);
  float yaw = atan2f(a[6], a[7]);
  float ca = fabsf(cosf(yaw)), sa = fabsf(sinf(yaw));
  float ex = 0.5f * (l * ca + w * sa);
  float ey = 0.5f * (l * sa + w * ca);
  float ez = 0.5f * h;
  mn[idx * 3 + 0] = x - ex; mn[idx * 3 + 1] = y - ey; mn[idx * 3 + 2] = z - ez;
  mx[idx * 3 + 0] = x + ex; mx[idx * 3 + 1] = y + ey; mx[idx * 3 + 2] = z + ez;
}

// ---------------- gather: key_feat, i2j_rm, conf_rm, key_in ----------------
__global__ __launch_bounds__(256) void gather_kernel(const float* __restrict__ b_feature,
                                                     const float* __restrict__ i2j_anchor,
                                                     const int* __restrict__ top_idx,
                                                     const float* __restrict__ conf,
                                                     const float* __restrict__ anc_w,
                                                     const float* __restrict__ anc_b,
                                                     const float* __restrict__ t_mlp,
                                                     float* __restrict__ key_feat,
                                                     float* __restrict__ conf_rm,
                                                     float* __restrict__ i2j_rm,
                                                     float* __restrict__ key_in) {
  int blk = blockIdx.x;  // i*4+jj
  int i = blk / NM1_, jj = blk % NM1_;
  int j = jj < i ? jj : jj + 1;
  int c = threadIdx.x;
  __shared__ float aw[AD_][D_];
#pragma unroll
  for (int r = 0; r < AD_; r++) aw[r][c] = anc_w[r * D_ + c];
  float ab = anc_b[c];
  float tv = t_mlp[(i * NM1_ + jj) * D_ + c];
  __syncthreads();
  for (int k = 0; k < K_; k++) {
    int idx = top_idx[j * K_ + k];
    float cf = conf[j * K_ + k];
    const float* src = b_feature + ((long)(j * A_ + idx)) * D_;
    float val = src[c];
    long mrow = (long)i * M_ + jj * K_ + k;
    key_feat[mrow * D_ + c] = val;
    const float* ap = i2j_anchor + ((long)((i * N_ + j) * A_ + idx)) * AD_;
    if (c < AD_) i2j_rm[mrow * AD_ + c] = ap[c];
    if (c == 0) conf_rm[mrow] = cf;
    float pos = ab + tv;
#pragma unroll
    for (int r = 0; r < AD_; r++) pos += ap[r] * aw[r][c];
    key_in[mrow * D_ + c] = val + pos;
  }
}

// ---------------- inside mask (conf folded in) ----------------
__global__ __launch_bounds__(256) void inside_kernel(const float* __restrict__ i2j_rm,
                                                     const float* __restrict__ conf_rm,
                                                     const float* __restrict__ mn,
                                                     const float* __restrict__ mx,
                                                     float* __restrict__ inside) {
  int row = blockIdx.x;  // i*900+a
  int i = row / A_;
  float mn0 = mn[row * 3 + 0], mn1 = mn[row * 3 + 1], mn2 = mn[row * 3 + 2];
  float mx0 = mx[row * 3 + 0], mx1 = mx[row * 3 + 1], mx2 = mx[row * 3 + 2];
#pragma unroll
  for (int it = 0; it < 5; it++) {
    int m = it * 256 + threadIdx.x;
    if (m < M_) {
      const float* cp = i2j_rm + ((long)i * M_ + m) * AD_;
      float c0 = cp[0], c1 = cp[1], c2 = cp[2];
      bool ins = (c0 >= mn0) && (c0 <= mx0) && (c1 >= mn1) && (c1 <= mx1) && (c2 >= mn2) && (c2 <= mx2);
      inside[(long)row * M_ + m] = ins ? conf_rm[(long)i * M_ + m] : 0.0f;
    }
  }
}

// ---------------- distance-bias precompute: Lbuf[i][m][a] = log1p(dist) ----------------
__global__ __launch_bounds__(256) void bias_kernel(const float* __restrict__ ban,
                                                   const float* __restrict__ i2j_rm,
                                                   float* __restrict__ Lbuf) {
  int i = blockIdx.x, m = blockIdx.y;
  const float* cp = i2j_rm + ((long)i * M_ + m) * AD_;
  float cx = cp[0], cy = cp[1];
  for (int a = threadIdx.x; a < A_; a += 256) {
    float dx = ban[(long)(i * A_ + a) * AD_ + 0] - cx;
    float dy = ban[(long)(i * A_ + a) * AD_ + 1] - cy;
    float dist = sqrtf(dx * dx + dy * dy + 1e-12f);
    Lbuf[((long)i * M_ + m) * A_ + a] = log1pf(dist);
  }
}

// ---------------- generic batched GEMM: C = A@B (+bias) (+res) ----------------
__global__ __launch_bounds__(256) void gemm_kernel(const float* __restrict__ A,
                                                   const float* __restrict__ B,
                                                   const float* __restrict__ bias,
                                                   const float* __restrict__ res,
                                                   float* __restrict__ C,
                                                   int Mr, int Nc, int Kc,
                                                   long sA, long sB, long sC) {
  int bz = blockIdx.z;
  A += (long)bz * sA;
  B += (long)bz * sB;
  C += (long)bz * sC;
  if (res) res += (long)bz * sC;
  __shared__ float As[16][65];
  __shared__ float Bs[16][65];
  int m0 = blockIdx.x * 64, n0 = blockIdx.y * 64;
  int tid = threadIdx.x;
  int tx = tid % 16, ty = tid / 16;
  float acc[4][4] = {};
  for (int k0 = 0; k0 < Kc; k0 += 16) {
#pragma unroll
    for (int r = 0; r < 4; r++) {
      int l = r * 256 + tid;
      int mm = l >> 4, kk = l & 15;
      int gm = m0 + mm, gk = k0 + kk;
      As[kk][mm] = (gm < Mr && gk < Kc) ? A[(long)gm * Kc + gk] : 0.0f;
    }
#pragma unroll
    for (int r = 0; r < 4; r++) {
      int l = r * 256 + tid;
      int nn = l & 63, kk = l >> 6;
      int gk = k0 + kk, gn = n0 + nn;
      Bs[kk][nn] = (gk < Kc && gn < Nc) ? B[(long)gk * Nc + gn] : 0.0f;
    }
    __syncthreads();
#pragma unroll
    for (int kk = 0; kk < 16; kk++) {
      float av[4], bv[4];
#pragma unroll
      for (int ii = 0; ii < 4; ii++) av[ii] = As[kk][ty * 4 + ii];
#pragma unroll
      for (int jjv = 0; jjv < 4; jjv++) bv[jjv] = Bs[kk][tx * 4 + jjv];
#pragma unroll
      for (int ii = 0; ii < 4; ii++)
#pragma unroll
        for (int jjv = 0; jjv < 4; jjv++) acc[ii][jjv] += av[ii] * bv[jjv];
    }
    __syncthreads();
  }
#pragma unroll
  for (int ii = 0; ii < 4; ii++) {
    int gm = m0 + ty * 4 + ii;
    if (gm >= Mr) continue;
#pragma unroll
    for (int jjv = 0; jjv < 4; jjv++) {
      int gn = n0 + tx * 4 + jjv;
      if (gn >= Nc) continue;
      float v = acc[ii][jjv];
      if (bias) v += bias[gn];
      if (res) v += res[(long)gm * Nc + gn];
      C[(long)gm * Nc + gn] = v;
    }
  }
}

// ---------------- elementwise add ----------------
__global__ void add_kernel(const float* __restrict__ a, const float* __restrict__ b,
                           float* __restrict__ c, int n) {
  int i = blockIdx.x * 256 + threadIdx.x;
  if (i < n) c[i] = a[i] + b[i];
}

// ---------------- flash attention: 1 thread per query, m split 2-way in-block ----------------
__global__ __launch_bounds__(128) void attn_kernel(const float* __restrict__ qh,
                                                   const float* __restrict__ kh,
                                                   const float* __restrict__ vh,
                                                   const float* __restrict__ lm_rm,
                                                   const float* __restrict__ Lbuf,
                                                   float* __restrict__ out) {
  int ih = blockIdx.x;
  int i = ih >> 3, h = ih & 7;
  int a0 = blockIdx.y * QT_;
  int tid = threadIdx.x;
  int hl = tid >> 6;   // which m-half this thread works on
  int lt = tid & 63;   // query slot within tile
  int a = a0 + lt;
  bool active = a < A_;
  int a_ld = active ? a : A_ - 1;

  __shared__ float Ks[2][MC_][DH_];
  __shared__ float Vs[2][MC_][DH_];
  __shared__ float mbuf[QT_][34];

  float q[DH_], o[DH_];
  const float* qp = qh + ((long)(i * A_ + a_ld)) * D_ + h * DH_;
#pragma unroll
  for (int d4 = 0; d4 < 8; d4++) {
    float4 t = *(const float4*)(qp + d4 * 4);
    q[d4 * 4 + 0] = t.x; q[d4 * 4 + 1] = t.y; q[d4 * 4 + 2] = t.z; q[d4 * 4 + 3] = t.w;
  }
  float lmv = lm_rm[(long)(i * A_ + a_ld) * H_ + h];
#pragma unroll
  for (int d = 0; d < DH_; d++) o[d] = 0.0f;
  float m_run = -INFINITY, s = 0.0f;

  const float* kb = kh + (long)i * M_ * D_ + h * DH_;
  const float* vb = vh + (long)i * M_ * D_ + h * DH_;
  const float* lbase = Lbuf + (long)i * M_ * A_ + a_ld;
  int mbase = hl * HALFM_;

  for (int c = 0; c < CHUNKS_; c++) {
    int m0 = mbase + c * MC_;
    __syncthreads();
    // cooperative stage: each half's 64 threads load its own chunk
    for (int idx = lt; idx < MC_ * 8; idx += 64) {
      int row = idx >> 3, d4 = idx & 7;
      *(float4*)&Ks[hl][row][d4 * 4] = *(const float4*)(kb + (long)(m0 + row) * D_ + d4 * 4);
      *(float4*)&Vs[hl][row][d4 * 4] = *(const float4*)(vb + (long)(m0 + row) * D_ + d4 * 4);
    }
    __syncthreads();
    float lg[MC_];
    float cmax = -INFINITY;
#pragma unroll
    for (int mm = 0; mm < MC_; mm++) {
      float dot = 0.0f;
#pragma unroll
      for (int d = 0; d < DH_; d++) dot += q[d] * Ks[hl][mm][d];
      float L = lbase[(long)(m0 + mm) * A_];
      lg[mm] = dot * 0.17677669529663687f - L * lmv;
      cmax = fmaxf(cmax, lg[mm]);
    }
    float nm = fmaxf(m_run, cmax);
    float corr = __expf(m_run - nm);
    s *= corr;
#pragma unroll
    for (int d = 0; d < DH_; d++) o[d] *= corr;
    m_run = nm;
#pragma unroll
    for (int mm = 0; mm < MC_; mm++) {
      float p = __expf(lg[mm] - m_run);
      s += p;
#pragma unroll
      for (int d = 0; d < DH_; d++) o[d] += p * Vs[hl][mm][d];
    }
  }

  // merge the two m-halves
  __syncthreads();
  if (hl == 1) {
    mbuf[lt][0] = m_run;
    mbuf[lt][1] = s;
#pragma unroll
    for (int d = 0; d < DH_; d++) mbuf[lt][2 + d] = o[d];
  }
  __syncthreads();
  if (hl == 0 && active) {
    float m1 = mbuf[lt][0], s1 = mbuf[lt][1];
    float nm = fmaxf(m_run, m1);
    float e0 = __expf(m_run - nm), e1 = __expf(m1 - nm);
    float inv = 1.0f / (s * e0 + s1 * e1);
    float* op = out + ((long)(i * A_ + a)) * D_ + h * DH_;
#pragma unroll
    for (int d = 0; d < DH_; d++) op[d] = (o[d] * e0 + mbuf[lt][2 + d] * e1) * inv;
  }
}

// ---------------- LayerNorm ----------------
__global__ __launch_bounds__(256) void ln_kernel(const float* __restrict__ x,
                                                 const float* __restrict__ g,
                                                 const float* __restrict__ b,
                                                 float* __restrict__ out) {
  int row = blockIdx.x;
  int t = threadIdx.x;
  float v = x[(long)row * D_ + t];
  float s = v, sq = v * v;
#pragma unroll
  for (int o = 32; o; o >>= 1) {
    s += __shfl_xor(s, o, 64);
    sq += __shfl_xor(sq, o, 64);
  }
  __shared__ float ss[4], ssq[4];
  int wid = t >> 6, lane = t & 63;
  if (lane == 0) { ss[wid] = s; ssq[wid] = sq; }
  __syncthreads();
  float ts = ss[0] + ss[1] + ss[2] + ss[3];
  float tq = ssq[0] + ssq[1] + ssq[2] + ssq[3];
  float mean = ts / (float)D_;
  float var = tq / (float)D_ - mean * mean;
  out[(long)row * D_ + t] = (v - mean) * rsqrtf(var + 1e-5f) * g[t] + b[t];
}

extern "C" void kernel_launch(void* const* d_in, const int* in_sizes, int n_in,
                              void* d_out, int out_size, void* d_ws, size_t ws_size,
                              hipStream_t stream) {
  const float* i2j_anchor   = (const float*)d_in[0];
  const float* b_anchor     = (const float*)d_in[1];
  const float* b_feature    = (const float*)d_in[2];
  const float* tm           = (const float*)d_in[3];
  const float* anchor_embed = (const float*)d_in[4];
  const float* w_roi  = (const float*)d_in[5];
  const float* b_roi  = (const float*)d_in[6];
  const float* bn_g   = (const float*)d_in[7];
  const float* bn_b   = (const float*)d_in[8];
  const float* fc1_w  = (const float*)d_in[9];
  const float* fc1_b  = (const float*)d_in[10];
  const float* fc2_w  = (const float*)d_in[11];
  const float* fc2_b  = (const float*)d_in[12];
  const float* anc_w  = (const float*)d_in[13];
  const float* anc_b  = (const float*)d_in[14];
  const float* lam_w  = (const float*)d_in[15];
  const float* lam_b  = (const float*)d_in[16];
  const float* wq = (const float*)d_in[17];
  const float* bq = (const float*)d_in[18];
  const float* wk = (const float*)d_in[19];
  const float* bk = (const float*)d_in[20];
  const float* wv = (const float*)d_in[21];
  const float* bv = (const float*)d_in[22];
  const float* wo = (const float*)d_in[23];
  const float* bo = (const float*)d_in[24];
  const float* ln_g = (const float*)d_in[25];
  const float* ln_b = (const float*)d_in[26];

  float* ws = (float*)d_ws;
  size_t off = 0;
  auto alloc = [&](size_t n) { float* p = ws + off; off += n; return p; };

  float* scores    = alloc(N_ * A_);
  int*   top_idx   = (int*)alloc(N_ * K_);
  float* conf      = alloc(N_ * K_);
  float* t_mlp     = alloc(20 * D_);
  float* bmn       = alloc(N_ * A_ * 3);
  float* bmx       = alloc(N_ * A_ * 3);
  float* key_feat  = alloc((size_t)N_ * M_ * D_);
  float* conf_rm   = alloc((size_t)N_ * M_);
  float* i2j_rm    = alloc((size_t)N_ * M_ * AD_);
  float* key_in    = alloc((size_t)N_ * M_ * D_);
  float* inside    = alloc((size_t)N_ * A_ * M_);   // later reused as Lbuf [i][m][a]
  float* bf_upd    = alloc((size_t)N_ * A_ * D_);
  float* q_in      = alloc((size_t)N_ * A_ * D_);
  float* qhb       = alloc((size_t)N_ * A_ * D_);
  float* kh_rm     = alloc((size_t)N_ * M_ * D_);
  float* vh_rm     = alloc((size_t)N_ * M_ * D_);
  float* lm_rm     = alloc((size_t)N_ * A_ * H_);
  float* att_out   = alloc((size_t)N_ * A_ * D_);
  float* res_buf   = alloc((size_t)N_ * A_ * D_);
  float* Lbuf      = inside;  // alias: inside is dead after agg GEMM

  // 1. scores
  score_kernel<<<(N_ * A_ + 3) / 4, 256, 0, stream>>>(b_feature, w_roi, b_roi, scores);
  // 2. top-k
  topk_kernel<<<N_, 1024, 0, stream>>>(scores, top_idx, conf);
  // 3. tiny MLP
  mlp_kernel<<<1, 256, 0, stream>>>(tm, bn_g, bn_b, fc1_w, fc1_b, fc2_w, fc2_b, t_mlp);
  // 4. bbox
  bbox_kernel<<<(N_ * A_ + 255) / 256, 256, 0, stream>>>(b_anchor, bmn, bmx);
  // 5. gather
  gather_kernel<<<N_ * NM1_, 256, 0, stream>>>(b_feature, i2j_anchor, top_idx, conf,
                                               anc_w, anc_b, t_mlp,
                                               key_feat, conf_rm, i2j_rm, key_in);
  // 6. inside mask (with conf folded in)
  inside_kernel<<<N_ * A_, 256, 0, stream>>>(i2j_rm, conf_rm, bmn, bmx, inside);
  // 7. agg GEMM: bf_upd = inside @ key_feat + b_feature   (batched over i)
  gemm_kernel<<<dim3(15, 4, N_), 256, 0, stream>>>(inside, key_feat, nullptr, b_feature, bf_upd,
                                                   A_, D_, M_,
                                                   (long)A_ * M_, (long)M_ * D_, (long)A_ * D_);
  // 8. bias precompute (reuses inside's memory)
  bias_kernel<<<dim3(N_, M_), 256, 0, stream>>>(b_anchor, i2j_rm, Lbuf);
  // 9. q_in = bf_upd + anchor_embed
  add_kernel<<<(N_ * A_ * D_ + 255) / 256, 256, 0, stream>>>(bf_upd, anchor_embed, q_in, N_ * A_ * D_);
  // 10. lm = bf_upd @ lam_w + lam_b   (4500 x 8)
  gemm_kernel<<<dim3(71, 1, 1), 256, 0, stream>>>(bf_upd, lam_w, lam_b, nullptr, lm_rm,
                                                  N_ * A_, H_, D_, 0, 0, 0);
  // 11. qh = q_in @ wq + bq
  gemm_kernel<<<dim3(71, 4, 1), 256, 0, stream>>>(q_in, wq, bq, nullptr, qhb,
                                                  N_ * A_, D_, D_, 0, 0, 0);
  // 12. kh = key_in @ wk + bk
  gemm_kernel<<<dim3(94, 4, 1), 256, 0, stream>>>(key_in, wk, bk, nullptr, kh_rm,
                                                  N_ * M_, D_, D_, 0, 0, 0);
  // 13. vh = key_feat @ wv + bv
  gemm_kernel<<<dim3(94, 4, 1), 256, 0, stream>>>(key_feat, wv, bv, nullptr, vh_rm,
                                                  N_ * M_, D_, D_, 0, 0, 0);
  // 14. flash attention
  attn_kernel<<<dim3(N_ * H_, (A_ + QT_ - 1) / QT_), 128, 0, stream>>>(qhb, kh_rm, vh_rm,
                                                                       lm_rm, Lbuf, att_out);
  // 15. out projection + residual
  gemm_kernel<<<dim3(71, 4, 1), 256, 0, stream>>>(att_out, wo, bo, bf_upd, res_buf,
                                                  N_ * A_, D_, D_, 0, 0, 0);
  // 16. LayerNorm -> d_out
  ln_kernel<<<N_ * A_, 256, 0, stream>>>(res_buf, ln_g, ln_b, (float*)d_out);
}